// Round 10
// baseline (91.001 us; speedup 1.0000x reference)
//
#include <hip/hip_runtime.h>
#include <stdint.h>

// DetectionLoss for B=16, N=884736. Output: [cls_pos_loss, cls_neg_loss].
//
// R9 counters: passA flat at ~58us (1340 instr/wave vs ~590 threefry floor) —
// the store/staging machinery costs as much as it replaced. R10: passA = pure
// threefry + target-only loads + per-slot wave BALLOT masks (64B/wave store);
// candidates expanded in a tiny 1-wave-per-block kernel (recompute threefry
// for the 1.45%, gather pred/mask scattered, pack rec, build histogram).
// B1 folded into B2 (redundant per-block scan). Selection math unchanged.

#define BATCH 16
#define NPTS 884736u
#define THRESH_KEY 8266976u   // keep keys >= this (tail fraction 0.01450)
#define CAP 15360u            // candidate capacity/sample (mean ~12825, sd ~112)
#define BCAP 64
#define KSEL 10000u
#define NBIN 1024             // bin = (key-THRESH_KEY)>>7 -> bins 0..950, ~13.5/bin
#define EPT 8u
#define NBLK 432u             // passA grid.x; NBLK*2048 = NPTS

// ws layout:
//   [0,4096)          hdr: per-sample 256B line
//     +0 f32 pos_sum, +4 u32 npos, +8 u32 cand_cnt, +12 f32 neg_result,
//     +16 u32 boundary_bin (0xFFFFFFFF = take_all), +20 u32 need,
//     +24 f32 neg_partial_sum, +28 u32 boundary_cnt
//   [4096,69632)      hist: 16 x 1024 u32
//   [69632,81920)     blk_key/idx/x: 3 x 16 x 64
//   [81920,1851392)   cand_mask: u64[16][432][4 waves][8 slots]
//   [1851392,...)     g_rec 16*cap u64, then g_x 16*cap f32

struct KeyPairs { unsigned k[2 * BATCH]; };

__host__ __device__ __forceinline__ void tf2x32(unsigned k0, unsigned k1,
                                                unsigned x0, unsigned x1,
                                                unsigned& o0, unsigned& o1)
{
  unsigned ks0 = k0, ks1 = k1, ks2 = k0 ^ k1 ^ 0x1BD11BDAu;
  x0 += ks0; x1 += ks1;
#define TF_R(r) { x0 += x1; x1 = (x1 << (r)) | (x1 >> (32 - (r))); x1 ^= x0; }
  TF_R(13) TF_R(15) TF_R(26) TF_R(6)
  x0 += ks1; x1 += ks2 + 1u;
  TF_R(17) TF_R(29) TF_R(16) TF_R(24)
  x0 += ks2; x1 += ks0 + 2u;
  TF_R(13) TF_R(15) TF_R(26) TF_R(6)
  x0 += ks0; x1 += ks1 + 3u;
  TF_R(17) TF_R(29) TF_R(16) TF_R(24)
  x0 += ks1; x1 += ks2 + 4u;
  TF_R(13) TF_R(15) TF_R(26) TF_R(6)
  x0 += ks2; x1 += ks0 + 5u;
#undef TF_R
  o0 = x0; o1 = x1;
}

__device__ __forceinline__ float lossf(float x, float t, float m)
{
  float e  = __expf(-x);
  float p  = __fdividef(1.0f, 1.0f + e);
  p = fminf(fmaxf(p, 1e-4f), 1.0f - 1e-4f);
  bool is_pos = (t == 1.0f);
  float alpha = is_pos ? 0.75f : 0.25f;
  float pw = is_pos ? (1.0f - p) : p;
  float soft = __logf(1.0f + __expf(-fabsf(x)));
  float bce = fmaxf(x, 0.0f) - x * t + soft;
  float L = (m == 0.0f) ? alpha * pw * pw * bce : 0.0f;
  if (is_pos && p < 0.8f) L *= 4.0f;
  if (!is_pos && p > 0.5f)
    L *= 1.5f + fminf(fmaxf((p - 0.5f) * 5.0f, 0.0f), 1.0f) * 0.5f;
  return L;
}

__global__ __launch_bounds__(256) void passA(
    const float* __restrict__ pred, const float* __restrict__ target,
    const float* __restrict__ mask, char* __restrict__ hdr,
    unsigned long long* __restrict__ cand_mask, KeyPairs kp)
{
  const int b = blockIdx.y;
  const int tid = threadIdx.x;
  const unsigned i0 = (blockIdx.x * 256u + tid) * EPT;
  const size_t off = (size_t)b * NPTS + i0;
  const unsigned k0 = kp.k[2 * b], k1 = kp.k[2 * b + 1];
  char* line = hdr + (size_t)b * 256;

  float4 t4a = *reinterpret_cast<const float4*>(target + off);
  float4 t4b = *reinterpret_cast<const float4*>(target + off + 4);
  float tv[8] = { t4a.x, t4a.y, t4a.z, t4a.w, t4b.x, t4b.y, t4b.z, t4b.w };

  unsigned key[8];
#pragma unroll
  for (int r = 0; r < 8; ++r) {
    unsigned o0, o1;
    tf2x32(k0, k1, 0u, i0 + (unsigned)r, o0, o1);   // partitionable: (0, i)
    key[r] = (o0 ^ o1) >> 9;                        // 23-bit order key
  }

  // per-slot candidate ballots (wave-wide), per-lane positive mask
  unsigned long long B0 = __ballot((tv[0] == 0.0f) && (key[0] >= THRESH_KEY));
  unsigned long long B1 = __ballot((tv[1] == 0.0f) && (key[1] >= THRESH_KEY));
  unsigned long long B2 = __ballot((tv[2] == 0.0f) && (key[2] >= THRESH_KEY));
  unsigned long long B3 = __ballot((tv[3] == 0.0f) && (key[3] >= THRESH_KEY));
  unsigned long long B4 = __ballot((tv[4] == 0.0f) && (key[4] >= THRESH_KEY));
  unsigned long long B5 = __ballot((tv[5] == 0.0f) && (key[5] >= THRESH_KEY));
  unsigned long long B6 = __ballot((tv[6] == 0.0f) && (key[6] >= THRESH_KEY));
  unsigned long long B7 = __ballot((tv[7] == 0.0f) && (key[7] >= THRESH_KEY));

  unsigned posm = 0;
#pragma unroll
  for (int r = 0; r < 8; ++r)
    if (tv[r] == 1.0f) posm |= (1u << r);

  const int wv = tid >> 6, lane = tid & 63;
  if (lane == 0) {
    unsigned long long* dst =
        cand_mask + ((size_t)((b * (int)NBLK + blockIdx.x) * 4 + wv)) * 8;
    reinterpret_cast<ulonglong2*>(dst)[0] = ulonglong2{B0, B1};
    reinterpret_cast<ulonglong2*>(dst)[1] = ulonglong2{B2, B3};
    reinterpret_cast<ulonglong2*>(dst)[2] = ulonglong2{B4, B5};
    reinterpret_cast<ulonglong2*>(dst)[3] = ulonglong2{B6, B7};
  }

  // positives: rare (P(thread)~0.4%) -> scalar loads + direct global atomics
  if (posm) {
    float psum = 0.0f;
#pragma unroll
    for (int r = 0; r < 8; ++r) {
      if (posm & (1u << r)) {
        float x = pred[off + r];
        float m = mask[off + r];
        psum += lossf(x, 1.0f, m);
      }
    }
    atomicAdd((float*)(line + 0), psum);
    atomicAdd((unsigned*)(line + 4), __popc(posm));
  }
}

// expand: 1 wave/block; 32 ballot words (= 2048 elements) per block.
// Recompute threefry for set bits, gather pred/mask, pack rec, build hist.
__global__ __launch_bounds__(64) void expand(
    const float* __restrict__ pred, const float* __restrict__ mask,
    char* __restrict__ hdr, const unsigned long long* __restrict__ cand_mask,
    unsigned* __restrict__ hist, unsigned long long* __restrict__ g_rec,
    float* __restrict__ g_x, unsigned cap, KeyPairs kp)
{
  const int b = blockIdx.y;
  const unsigned blk = blockIdx.x;
  const int lane = threadIdx.x;
  char* line = hdr + (size_t)b * 256;

  unsigned long long w = 0;
  if (lane < 32) w = cand_mask[((size_t)(b * (int)NBLK + (int)blk)) * 32 + lane];
  unsigned cnt = (unsigned)__popcll(w);

  unsigned pfx = cnt;                     // inclusive wave prefix sum
#pragma unroll
  for (int s = 1; s < 64; s <<= 1) {
    unsigned u = __shfl_up(pfx, s, 64);
    if (lane >= s) pfx += u;
  }
  unsigned total = __shfl(pfx, 63, 64);
  unsigned excl = pfx - cnt;
  unsigned gb_ = 0;
  if (lane == 63 && total) gb_ = atomicAdd((unsigned*)(line + 8), total);
  unsigned gbase = __shfl(gb_, 63, 64);

  const unsigned k0 = kp.k[2 * b], k1 = kp.k[2 * b + 1];
  const size_t sbase = (size_t)b * NPTS;
  unsigned j = 0;
  while (w) {
    int l = __ffsll(w) - 1;
    w &= w - 1ull;
    unsigned i = blk * 2048u + ((unsigned)lane >> 3) * 512u +
                 (unsigned)l * 8u + ((unsigned)lane & 7u);
    unsigned o0, o1;
    tf2x32(k0, k1, 0u, i, o0, o1);
    unsigned kk = (o0 ^ o1) >> 9;
    unsigned p = gbase + excl + j; ++j;
    if (p < cap) {
      size_t o = (size_t)b * cap + p;
      float m = mask[sbase + i];
      g_rec[o] = ((unsigned long long)kk << 20) | i;
      g_x[o]   = (m == 0.0f) ? pred[sbase + i] : -1000.0f;  // mask -> L==0
    }
    atomicAdd(&hist[b * NBIN + ((kk - THRESH_KEY) >> 7)], 1u);
  }
}

// B2 (includes old B1 per-block): boundary bin via hist suffix-scan, then
// 16 chunks/sample: sum losses in bins > B, collect boundary-bin entries.
__global__ __launch_bounds__(256) void passB2(
    char* __restrict__ hdr, const unsigned* __restrict__ hist,
    const unsigned long long* __restrict__ g_rec, const float* __restrict__ g_x,
    unsigned* __restrict__ blk_key, unsigned* __restrict__ blk_idx,
    float* __restrict__ blk_x, unsigned cap)
{
  const int b = blockIdx.y;
  const int tid = threadIdx.x;
  char* line = hdr + (size_t)b * 256;

  __shared__ unsigned h[NBIN];
  __shared__ unsigned chunk[256];
  __shared__ float    redf[256];
  __shared__ unsigned s_c, s_B, s_need;

  unsigned cnt = *(const unsigned*)(line + 8);
  if (cnt > cap) cnt = cap;
  const bool take_all = (cnt <= KSEL);
  unsigned Bbin = 0xFFFFFFFFu;

  if (!take_all) {
#pragma unroll
    for (int i = 0; i < NBIN / 256; ++i)
      h[tid + 256 * i] = hist[b * NBIN + tid + 256 * i];
    __syncthreads();
    unsigned cs = h[tid * 4] + h[tid * 4 + 1] + h[tid * 4 + 2] + h[tid * 4 + 3];
    chunk[tid] = cs;
    __syncthreads();
    for (int s = 1; s < 256; s <<= 1) {
      unsigned v2 = chunk[tid] + ((tid + s < 256) ? chunk[tid + s] : 0u);
      __syncthreads();
      chunk[tid] = v2;
      __syncthreads();
    }
    if (chunk[tid] >= KSEL && (tid == 255 || chunk[tid + 1] < KSEL)) s_c = tid;
    __syncthreads();
    if (tid == 0) {
      unsigned c = s_c;
      unsigned acc = (c < 255) ? chunk[c + 1] : 0u;
      unsigned B = c * 4;
      for (int bin = (int)c * 4 + 3; bin >= (int)c * 4; --bin) {
        unsigned hb = h[bin];
        if (acc + hb >= KSEL) { B = (unsigned)bin; break; }
        acc += hb;
      }
      s_B = B;
      s_need = KSEL - acc;
    }
    __syncthreads();
    Bbin = s_B;
  }
  if (blockIdx.x == 0 && tid == 0) {
    *(unsigned*)(line + 16) = Bbin;
    *(unsigned*)(line + 20) = take_all ? 0u : s_need;
  }

  const unsigned long long* Gr = g_rec + (size_t)b * cap;
  const float* Gx = g_x + (size_t)b * cap;
  float s = 0.0f;
  for (unsigned e = blockIdx.x * 256u + tid; e < cnt; e += 16u * 256u) {
    unsigned long long rc = Gr[e];
    float x = Gx[e];
    unsigned kk = (unsigned)(rc >> 20);
    unsigned bin = (kk - THRESH_KEY) >> 7;
    if (take_all || bin > Bbin) {
      s += lossf(x, 0.0f, 0.0f);
    } else if (bin == Bbin) {
      unsigned p = atomicAdd((unsigned*)(line + 28), 1u);
      if (p < BCAP) {
        blk_key[b * BCAP + p] = kk;
        blk_idx[b * BCAP + p] = (unsigned)(rc & 0xFFFFFu);
        blk_x[b * BCAP + p]   = x;
      }
    }
  }
  redf[tid] = s; __syncthreads();
  for (int st = 128; st > 0; st >>= 1) { if (tid < st) redf[tid] += redf[tid + st]; __syncthreads(); }
  if (tid == 0 && redf[0] != 0.0f) atomicAdd((float*)(line + 24), redf[0]);
}

// B3: boundary tie-break (key desc, idx asc) + final per-sample neg result
__global__ __launch_bounds__(256) void passB3(
    char* __restrict__ hdr, const unsigned long long* __restrict__ g_rec,
    const float* __restrict__ g_x, const unsigned* __restrict__ blk_key,
    const unsigned* __restrict__ blk_idx, const float* __restrict__ blk_x,
    unsigned cap)
{
  const int b = blockIdx.x;
  const int tid = threadIdx.x;
  char* line = hdr + (size_t)b * 256;

  __shared__ unsigned sbk[BCAP], sbi[BCAP];
  __shared__ float    sbx[BCAP];
  __shared__ unsigned redu[256];
  __shared__ float    redf[256];
  __shared__ unsigned s_fb, s_v, s_idxcut, s_k;
  __shared__ float    s_res;

  unsigned cnt = *(const unsigned*)(line + 8);
  if (cnt > cap) cnt = cap;
  const unsigned B = *(const unsigned*)(line + 16);
  const bool take_all = (B == 0xFFFFFFFFu);
  unsigned nb = *(const unsigned*)(line + 28);
  if (nb > BCAP) nb = BCAP;
  if (tid < BCAP && tid < nb) {
    sbk[tid] = blk_key[b * BCAP + tid];
    sbi[tid] = blk_idx[b * BCAP + tid];
    sbx[tid] = blk_x[b * BCAP + tid];
  }
  __syncthreads();

  if (tid == 0) {
    unsigned need = *(const unsigned*)(line + 20);
    unsigned m = (need < nb) ? need : nb;
    float bsum = 0.0f;
    unsigned vkey = 0, idxcut = 0xffffffffu;
    if (!take_all) {
      for (unsigned a = 0; a < m; ++a) {   // selection: key desc, idx asc
        unsigned best = a;
        for (unsigned q = a + 1; q < nb; ++q) {
          if (sbk[q] > sbk[best] ||
              (sbk[q] == sbk[best] && sbi[q] < sbi[best])) best = q;
        }
        unsigned tk = sbk[a]; sbk[a] = sbk[best]; sbk[best] = tk;
        unsigned ti = sbi[a]; sbi[a] = sbi[best]; sbi[best] = ti;
        float    tl = sbx[a]; sbx[a] = sbx[best]; sbx[best] = tl;
        bsum += lossf(sbx[a], 0.0f, 0.0f);
      }
      if (m > 0) { vkey = sbk[m - 1]; idxcut = sbi[m - 1]; }
    }
    float total = *(const float*)(line + 24) + bsum;
    unsigned nsel = take_all ? cnt : KSEL;
    unsigned np = *(const unsigned*)(line + 4);
    unsigned k = (np > 0u) ? ((100u * np < KSEL) ? 100u * np : KSEL) : 100u;
    s_fb = (k < nsel) ? 1u : 0u;
    s_res = total; s_v = vkey; s_idxcut = idxcut; s_k = k;
  }
  __syncthreads();

  if (s_fb) {
    // exact sum of k largest losses among selected (dead for this data)
    const unsigned long long* Gr = g_rec + (size_t)b * cap;
    const float* Gx = g_x + (size_t)b * cap;
    unsigned vkey = s_v, idxcut = s_idxcut, k = s_k;
    auto selp = [&](unsigned e) -> bool {
      if (take_all) return true;
      unsigned kk = (unsigned)(Gr[e] >> 20);
      unsigned bin = (kk - THRESH_KEY) >> 7;
      if (bin > B) return true;
      if (bin < B) return false;
      if (kk > vkey) return true;
      if (kk < vkey) return false;
      return (unsigned)(Gr[e] & 0xFFFFFu) <= idxcut;
    };
    auto countLossGe = [&](unsigned w) -> unsigned {
      unsigned c = 0;
      for (unsigned e = tid; e < cnt; e += 256)
        if (selp(e) && __float_as_uint(lossf(Gx[e], 0.0f, 0.0f)) >= w) c++;
      redu[tid] = c; __syncthreads();
      for (int s = 128; s > 0; s >>= 1) { if (tid < s) redu[tid] += redu[tid + s]; __syncthreads(); }
      unsigned r = redu[0]; __syncthreads();
      return r;
    };
    unsigned lo = 0u, hi = 0x7f7fffffu;
    while (lo < hi) {
      unsigned mid = lo + (hi - lo + 1u) / 2u;
      if (countLossGe(mid) >= k) lo = mid; else hi = mid - 1u;
    }
    unsigned cgt = countLossGe(lo + 1u);
    float s2 = 0.0f;
    for (unsigned e = tid; e < cnt; e += 256) {
      float L = lossf(Gx[e], 0.0f, 0.0f);
      if (selp(e) && __float_as_uint(L) > lo) s2 += L;
    }
    redf[tid] = s2; __syncthreads();
    for (int st = 128; st > 0; st >>= 1) { if (tid < st) redf[tid] += redf[tid + st]; __syncthreads(); }
    if (tid == 0) s_res = redf[0] + (float)(k - cgt) * __uint_as_float(lo);
    __syncthreads();
  }

  if (tid == 0) *(float*)(line + 12) = s_res;
}

__global__ void passC(const char* __restrict__ hdr, float* __restrict__ out)
{
  const int lane = threadIdx.x;
  float ps = 0.0f, ns = 0.0f;
  if (lane < BATCH) {
    const char* line = hdr + (size_t)lane * 256;
    unsigned np = *(const unsigned*)(line + 4);
    float denom = (np > 0u) ? fmaxf((float)np, 1.0f) : 1.0f;
    ps = (*(const float*)(line + 0)) / denom;
    ns = (*(const float*)(line + 12)) / denom;
  }
#pragma unroll
  for (int s = 8; s > 0; s >>= 1) {
    ps += __shfl_down(ps, s, 64);
    ns += __shfl_down(ns, s, 64);
  }
  if (lane == 0 && blockIdx.x == 0) {
    out[0] = ps / (float)BATCH;
    out[1] = ns / (float)BATCH;
  }
}

extern "C" void kernel_launch(void* const* d_in, const int* in_sizes, int n_in,
                              void* d_out, int out_size, void* d_ws, size_t ws_size,
                              hipStream_t stream)
{
  const float* pred   = (const float*)d_in[0];
  const float* target = (const float*)d_in[1];
  const float* mask   = (const float*)d_in[2];
  float* out = (float*)d_out;

  const size_t MASK_BYTES = (size_t)BATCH * NBLK * 4 * 8 * 8;   // 1,769,472
  const size_t FIXED = 4096 + (size_t)BATCH * NBIN * 4
                     + 3 * (size_t)BATCH * BCAP * 4 + MASK_BYTES; // 1,851,392
  size_t avail = (ws_size > FIXED) ? (ws_size - FIXED) : 0;
  unsigned cap = (unsigned)(avail / ((size_t)BATCH * 12));
  if (cap > CAP) cap = CAP;
  if (cap == 0 || out_size < 2) {
    hipMemsetAsync(d_out, 0, sizeof(float) * (out_size > 0 ? out_size : 1), stream);
    return;
  }

  char* ws = (char*)d_ws;
  char*     hdr     = ws;
  unsigned* hist    = (unsigned*)(ws + 4096);
  unsigned* blk_key = (unsigned*)(ws + 4096 + (size_t)BATCH * NBIN * 4);
  unsigned* blk_idx = blk_key + BATCH * BCAP;
  float*    blk_x   = (float*)(blk_idx + BATCH * BCAP);
  unsigned long long* cand_mask =
      (unsigned long long*)(ws + 4096 + (size_t)BATCH * NBIN * 4
                               + 3 * (size_t)BATCH * BCAP * 4);
  unsigned long long* g_rec = (unsigned long long*)(ws + FIXED);
  float*    g_x     = (float*)(ws + FIXED + (size_t)BATCH * cap * 8);

  KeyPairs kp;
  for (unsigned b = 0; b < BATCH; ++b) {
    unsigned o0, o1;
    tf2x32(0u, 42u, 0u, b, o0, o1);
    kp.k[2 * b] = o0; kp.k[2 * b + 1] = o1;
  }

  hipMemsetAsync(ws, 0, 4096 + (size_t)BATCH * NBIN * 4, stream);  // hdr + hist

  passA<<<dim3(NBLK, BATCH), 256, 0, stream>>>(pred, target, mask, hdr,
                                               cand_mask, kp);
  expand<<<dim3(NBLK, BATCH), 64, 0, stream>>>(pred, mask, hdr, cand_mask,
                                               hist, g_rec, g_x, cap, kp);
  passB2<<<dim3(16, BATCH), 256, 0, stream>>>(hdr, hist, g_rec, g_x,
                                              blk_key, blk_idx, blk_x, cap);
  passB3<<<BATCH, 256, 0, stream>>>(hdr, g_rec, g_x, blk_key, blk_idx, blk_x, cap);
  passC<<<1, 64, 0, stream>>>(hdr, out);
}

// Round 11
// 88.078 us; speedup vs baseline: 1.0332x; 1.0332x over previous
//
#include <hip/hip_runtime.h>
#include <stdint.h>

// DetectionLoss for B=16, N=884736. Output: [cls_pos_loss, cls_neg_loss].
//
// R10 counters: passA 41.5us (ballot scheme works; still ~1100 instr/wave vs
// ~620 threefry core — suspect non-fused rotates = +320), expand ~20us
// (1-wave blocks, serial ffs + dependent scattered gathers = latency-bound).
// R11: (1) __builtin_rotateleft32 -> v_alignbit_b32 (1 instr/rotate);
// (2) expand rebuilt: 256-thread blocks, 16384 elems/block (54x16 grid),
// one ballot word/thread, wave-shfl+LDS prefix, 1 atomic/block, ~1 cand/thread.
// Selection math unchanged (absmax 0.0 expected).

#define BATCH 16
#define NPTS 884736u
#define THRESH_KEY 8266976u   // keep keys >= this (tail fraction 0.01450)
#define CAP 15360u            // candidate capacity/sample (mean ~12825, sd ~112)
#define BCAP 64
#define KSEL 10000u
#define NBIN 1024             // bin = (key-THRESH_KEY)>>7 -> bins 0..950, ~13.5/bin
#define EPT 8u
#define NBLK 432u             // passA grid.x; NBLK*2048 = NPTS
#define EBLK 8u               // passA blocks per expand block (16384 elems)

// ws layout:
//   [0,4096)          hdr: per-sample 256B line
//     +0 f32 pos_sum, +4 u32 npos, +8 u32 cand_cnt, +12 f32 neg_result,
//     +16 u32 boundary_bin (0xFFFFFFFF = take_all), +20 u32 need,
//     +24 f32 neg_partial_sum, +28 u32 boundary_cnt
//   [4096,69632)      hist: 16 x 1024 u32
//   [69632,81920)     blk_key/idx/x: 3 x 16 x 64
//   [81920,1851392)   cand_mask: u64[16][432][4 waves][8 slots]
//   [1851392,...)     g_rec 16*cap u64, then g_x 16*cap f32

struct KeyPairs { unsigned k[2 * BATCH]; };

__host__ __device__ __forceinline__ void tf2x32(unsigned k0, unsigned k1,
                                                unsigned x0, unsigned x1,
                                                unsigned& o0, unsigned& o1)
{
  unsigned ks0 = k0, ks1 = k1, ks2 = k0 ^ k1 ^ 0x1BD11BDAu;
  x0 += ks0; x1 += ks1;
#define TF_R(r) { x0 += x1; x1 = __builtin_rotateleft32(x1, r); x1 ^= x0; }
  TF_R(13) TF_R(15) TF_R(26) TF_R(6)
  x0 += ks1; x1 += ks2 + 1u;
  TF_R(17) TF_R(29) TF_R(16) TF_R(24)
  x0 += ks2; x1 += ks0 + 2u;
  TF_R(13) TF_R(15) TF_R(26) TF_R(6)
  x0 += ks0; x1 += ks1 + 3u;
  TF_R(17) TF_R(29) TF_R(16) TF_R(24)
  x0 += ks1; x1 += ks2 + 4u;
  TF_R(13) TF_R(15) TF_R(26) TF_R(6)
  x0 += ks2; x1 += ks0 + 5u;
#undef TF_R
  o0 = x0; o1 = x1;
}

__device__ __forceinline__ float lossf(float x, float t, float m)
{
  float e  = __expf(-x);
  float p  = __fdividef(1.0f, 1.0f + e);
  p = fminf(fmaxf(p, 1e-4f), 1.0f - 1e-4f);
  bool is_pos = (t == 1.0f);
  float alpha = is_pos ? 0.75f : 0.25f;
  float pw = is_pos ? (1.0f - p) : p;
  float soft = __logf(1.0f + __expf(-fabsf(x)));
  float bce = fmaxf(x, 0.0f) - x * t + soft;
  float L = (m == 0.0f) ? alpha * pw * pw * bce : 0.0f;
  if (is_pos && p < 0.8f) L *= 4.0f;
  if (!is_pos && p > 0.5f)
    L *= 1.5f + fminf(fmaxf((p - 0.5f) * 5.0f, 0.0f), 1.0f) * 0.5f;
  return L;
}

__global__ __launch_bounds__(256) void passA(
    const float* __restrict__ pred, const float* __restrict__ target,
    const float* __restrict__ mask, char* __restrict__ hdr,
    unsigned long long* __restrict__ cand_mask, KeyPairs kp)
{
  const int b = blockIdx.y;
  const int tid = threadIdx.x;
  const unsigned i0 = (blockIdx.x * 256u + tid) * EPT;
  const size_t off = (size_t)b * NPTS + i0;
  const unsigned k0 = kp.k[2 * b], k1 = kp.k[2 * b + 1];
  char* line = hdr + (size_t)b * 256;

  float4 t4a = *reinterpret_cast<const float4*>(target + off);
  float4 t4b = *reinterpret_cast<const float4*>(target + off + 4);
  float tv[8] = { t4a.x, t4a.y, t4a.z, t4a.w, t4b.x, t4b.y, t4b.z, t4b.w };

  unsigned key[8];
#pragma unroll
  for (int r = 0; r < 8; ++r) {
    unsigned o0, o1;
    tf2x32(k0, k1, 0u, i0 + (unsigned)r, o0, o1);   // partitionable: (0, i)
    key[r] = (o0 ^ o1) >> 9;                        // 23-bit order key
  }

  // per-slot candidate ballots (wave-wide), per-lane positive mask
  unsigned long long B0 = __ballot((tv[0] == 0.0f) && (key[0] >= THRESH_KEY));
  unsigned long long B1 = __ballot((tv[1] == 0.0f) && (key[1] >= THRESH_KEY));
  unsigned long long B2 = __ballot((tv[2] == 0.0f) && (key[2] >= THRESH_KEY));
  unsigned long long B3 = __ballot((tv[3] == 0.0f) && (key[3] >= THRESH_KEY));
  unsigned long long B4 = __ballot((tv[4] == 0.0f) && (key[4] >= THRESH_KEY));
  unsigned long long B5 = __ballot((tv[5] == 0.0f) && (key[5] >= THRESH_KEY));
  unsigned long long B6 = __ballot((tv[6] == 0.0f) && (key[6] >= THRESH_KEY));
  unsigned long long B7 = __ballot((tv[7] == 0.0f) && (key[7] >= THRESH_KEY));

  unsigned posm = 0;
#pragma unroll
  for (int r = 0; r < 8; ++r)
    if (tv[r] == 1.0f) posm |= (1u << r);

  const int wv = tid >> 6, lane = tid & 63;
  if (lane == 0) {
    unsigned long long* dst =
        cand_mask + ((size_t)((b * (int)NBLK + blockIdx.x) * 4 + wv)) * 8;
    reinterpret_cast<ulonglong2*>(dst)[0] = ulonglong2{B0, B1};
    reinterpret_cast<ulonglong2*>(dst)[1] = ulonglong2{B2, B3};
    reinterpret_cast<ulonglong2*>(dst)[2] = ulonglong2{B4, B5};
    reinterpret_cast<ulonglong2*>(dst)[3] = ulonglong2{B6, B7};
  }

  // positives: rare (P(thread)~0.4%) -> scalar loads + direct global atomics
  if (posm) {
    float psum = 0.0f;
#pragma unroll
    for (int r = 0; r < 8; ++r) {
      if (posm & (1u << r)) {
        float x = pred[off + r];
        float m = mask[off + r];
        psum += lossf(x, 1.0f, m);
      }
    }
    atomicAdd((float*)(line + 0), psum);
    atomicAdd((unsigned*)(line + 4), __popc(posm));
  }
}

// expand: 256 threads/block, one ballot word per thread (16384 elems/block).
// Wave-shfl + LDS prefix -> one global atomic/block; ~1 candidate/thread:
// recompute threefry, gather pred/mask, pack rec, build histogram.
__global__ __launch_bounds__(256) void expand(
    const float* __restrict__ pred, const float* __restrict__ mask,
    char* __restrict__ hdr, const unsigned long long* __restrict__ cand_mask,
    unsigned* __restrict__ hist, unsigned long long* __restrict__ g_rec,
    float* __restrict__ g_x, unsigned cap, KeyPairs kp)
{
  const int b = blockIdx.y;
  const int tid = threadIdx.x;
  const int lane = tid & 63, w = tid >> 6;
  char* line = hdr + (size_t)b * 256;

  // word (blk_l, wv, r):  tid = blk_l*32 + wv*8 + r
  const unsigned blk_l = (unsigned)tid >> 5;
  const unsigned wv    = ((unsigned)tid >> 3) & 3u;
  const unsigned r     = (unsigned)tid & 7u;
  const unsigned blk   = blockIdx.x * EBLK + blk_l;
  unsigned long long cw =
      cand_mask[((size_t)(b * (int)NBLK + (int)blk) * 4 + wv) * 8 + r];
  // element for bit l: i = blk*2048 + wv*512 + l*8 + r
  const unsigned ibase = blk * 2048u + wv * 512u + r;

  unsigned cnt = (unsigned)__popcll(cw);
  unsigned pfx = cnt;                       // wave-inclusive prefix
#pragma unroll
  for (int s = 1; s < 64; s <<= 1) {
    unsigned u = __shfl_up(pfx, s, 64);
    if (lane >= s) pfx += u;
  }
  __shared__ unsigned wt[4];
  __shared__ unsigned s_gb;
  if (lane == 63) wt[w] = pfx;
  __syncthreads();
  if (tid == 0) {
    unsigned tot = wt[0] + wt[1] + wt[2] + wt[3];
    s_gb = tot ? atomicAdd((unsigned*)(line + 8), tot) : 0u;
  }
  __syncthreads();
  unsigned woff = 0;
#pragma unroll
  for (int q = 0; q < 4; ++q) if (q < w) woff += wt[q];
  unsigned gbase = s_gb + woff + (pfx - cnt);

  const unsigned k0 = kp.k[2 * b], k1 = kp.k[2 * b + 1];
  const size_t sbase = (size_t)b * NPTS;
  unsigned j = 0;
  while (cw) {
    int l = __ffsll(cw) - 1;
    cw &= cw - 1ull;
    unsigned i = ibase + (unsigned)l * 8u;
    unsigned o0, o1;
    tf2x32(k0, k1, 0u, i, o0, o1);
    unsigned kk = (o0 ^ o1) >> 9;
    unsigned p = gbase + j; ++j;
    if (p < cap) {
      size_t o = (size_t)b * cap + p;
      float m = mask[sbase + i];
      g_rec[o] = ((unsigned long long)kk << 20) | i;
      g_x[o]   = (m == 0.0f) ? pred[sbase + i] : -1000.0f;  // mask -> L==0
    }
    atomicAdd(&hist[b * NBIN + ((kk - THRESH_KEY) >> 7)], 1u);
  }
}

// B2: boundary bin via hist suffix-scan (per block), then 16 chunks/sample:
// sum losses in bins > B, collect boundary-bin entries.
__global__ __launch_bounds__(256) void passB2(
    char* __restrict__ hdr, const unsigned* __restrict__ hist,
    const unsigned long long* __restrict__ g_rec, const float* __restrict__ g_x,
    unsigned* __restrict__ blk_key, unsigned* __restrict__ blk_idx,
    float* __restrict__ blk_x, unsigned cap)
{
  const int b = blockIdx.y;
  const int tid = threadIdx.x;
  char* line = hdr + (size_t)b * 256;

  __shared__ unsigned h[NBIN];
  __shared__ unsigned chunk[256];
  __shared__ float    redf[256];
  __shared__ unsigned s_c, s_B, s_need;

  unsigned cnt = *(const unsigned*)(line + 8);
  if (cnt > cap) cnt = cap;
  const bool take_all = (cnt <= KSEL);
  unsigned Bbin = 0xFFFFFFFFu;

  if (!take_all) {
#pragma unroll
    for (int i = 0; i < NBIN / 256; ++i)
      h[tid + 256 * i] = hist[b * NBIN + tid + 256 * i];
    __syncthreads();
    unsigned cs = h[tid * 4] + h[tid * 4 + 1] + h[tid * 4 + 2] + h[tid * 4 + 3];
    chunk[tid] = cs;
    __syncthreads();
    for (int s = 1; s < 256; s <<= 1) {
      unsigned v2 = chunk[tid] + ((tid + s < 256) ? chunk[tid + s] : 0u);
      __syncthreads();
      chunk[tid] = v2;
      __syncthreads();
    }
    if (chunk[tid] >= KSEL && (tid == 255 || chunk[tid + 1] < KSEL)) s_c = tid;
    __syncthreads();
    if (tid == 0) {
      unsigned c = s_c;
      unsigned acc = (c < 255) ? chunk[c + 1] : 0u;
      unsigned B = c * 4;
      for (int bin = (int)c * 4 + 3; bin >= (int)c * 4; --bin) {
        unsigned hb = h[bin];
        if (acc + hb >= KSEL) { B = (unsigned)bin; break; }
        acc += hb;
      }
      s_B = B;
      s_need = KSEL - acc;
    }
    __syncthreads();
    Bbin = s_B;
  }
  if (blockIdx.x == 0 && tid == 0) {
    *(unsigned*)(line + 16) = Bbin;
    *(unsigned*)(line + 20) = take_all ? 0u : s_need;
  }

  const unsigned long long* Gr = g_rec + (size_t)b * cap;
  const float* Gx = g_x + (size_t)b * cap;
  float s = 0.0f;
  for (unsigned e = blockIdx.x * 256u + tid; e < cnt; e += 16u * 256u) {
    unsigned long long rc = Gr[e];
    float x = Gx[e];
    unsigned kk = (unsigned)(rc >> 20);
    unsigned bin = (kk - THRESH_KEY) >> 7;
    if (take_all || bin > Bbin) {
      s += lossf(x, 0.0f, 0.0f);
    } else if (bin == Bbin) {
      unsigned p = atomicAdd((unsigned*)(line + 28), 1u);
      if (p < BCAP) {
        blk_key[b * BCAP + p] = kk;
        blk_idx[b * BCAP + p] = (unsigned)(rc & 0xFFFFFu);
        blk_x[b * BCAP + p]   = x;
      }
    }
  }
  redf[tid] = s; __syncthreads();
  for (int st = 128; st > 0; st >>= 1) { if (tid < st) redf[tid] += redf[tid + st]; __syncthreads(); }
  if (tid == 0 && redf[0] != 0.0f) atomicAdd((float*)(line + 24), redf[0]);
}

// B3: boundary tie-break (key desc, idx asc) + final per-sample neg result
__global__ __launch_bounds__(256) void passB3(
    char* __restrict__ hdr, const unsigned long long* __restrict__ g_rec,
    const float* __restrict__ g_x, const unsigned* __restrict__ blk_key,
    const unsigned* __restrict__ blk_idx, const float* __restrict__ blk_x,
    unsigned cap)
{
  const int b = blockIdx.x;
  const int tid = threadIdx.x;
  char* line = hdr + (size_t)b * 256;

  __shared__ unsigned sbk[BCAP], sbi[BCAP];
  __shared__ float    sbx[BCAP];
  __shared__ unsigned redu[256];
  __shared__ float    redf[256];
  __shared__ unsigned s_fb, s_v, s_idxcut, s_k;
  __shared__ float    s_res;

  unsigned cnt = *(const unsigned*)(line + 8);
  if (cnt > cap) cnt = cap;
  const unsigned B = *(const unsigned*)(line + 16);
  const bool take_all = (B == 0xFFFFFFFFu);
  unsigned nb = *(const unsigned*)(line + 28);
  if (nb > BCAP) nb = BCAP;
  if (tid < BCAP && tid < nb) {
    sbk[tid] = blk_key[b * BCAP + tid];
    sbi[tid] = blk_idx[b * BCAP + tid];
    sbx[tid] = blk_x[b * BCAP + tid];
  }
  __syncthreads();

  if (tid == 0) {
    unsigned need = *(const unsigned*)(line + 20);
    unsigned m = (need < nb) ? need : nb;
    float bsum = 0.0f;
    unsigned vkey = 0, idxcut = 0xffffffffu;
    if (!take_all) {
      for (unsigned a = 0; a < m; ++a) {   // selection: key desc, idx asc
        unsigned best = a;
        for (unsigned q = a + 1; q < nb; ++q) {
          if (sbk[q] > sbk[best] ||
              (sbk[q] == sbk[best] && sbi[q] < sbi[best])) best = q;
        }
        unsigned tk = sbk[a]; sbk[a] = sbk[best]; sbk[best] = tk;
        unsigned ti = sbi[a]; sbi[a] = sbi[best]; sbi[best] = ti;
        float    tl = sbx[a]; sbx[a] = sbx[best]; sbx[best] = tl;
        bsum += lossf(sbx[a], 0.0f, 0.0f);
      }
      if (m > 0) { vkey = sbk[m - 1]; idxcut = sbi[m - 1]; }
    }
    float total = *(const float*)(line + 24) + bsum;
    unsigned nsel = take_all ? cnt : KSEL;
    unsigned np = *(const unsigned*)(line + 4);
    unsigned k = (np > 0u) ? ((100u * np < KSEL) ? 100u * np : KSEL) : 100u;
    s_fb = (k < nsel) ? 1u : 0u;
    s_res = total; s_v = vkey; s_idxcut = idxcut; s_k = k;
  }
  __syncthreads();

  if (s_fb) {
    // exact sum of k largest losses among selected (dead for this data)
    const unsigned long long* Gr = g_rec + (size_t)b * cap;
    const float* Gx = g_x + (size_t)b * cap;
    unsigned vkey = s_v, idxcut = s_idxcut, k = s_k;
    auto selp = [&](unsigned e) -> bool {
      if (take_all) return true;
      unsigned kk = (unsigned)(Gr[e] >> 20);
      unsigned bin = (kk - THRESH_KEY) >> 7;
      if (bin > B) return true;
      if (bin < B) return false;
      if (kk > vkey) return true;
      if (kk < vkey) return false;
      return (unsigned)(Gr[e] & 0xFFFFFu) <= idxcut;
    };
    auto countLossGe = [&](unsigned w) -> unsigned {
      unsigned c = 0;
      for (unsigned e = tid; e < cnt; e += 256)
        if (selp(e) && __float_as_uint(lossf(Gx[e], 0.0f, 0.0f)) >= w) c++;
      redu[tid] = c; __syncthreads();
      for (int s = 128; s > 0; s >>= 1) { if (tid < s) redu[tid] += redu[tid + s]; __syncthreads(); }
      unsigned r = redu[0]; __syncthreads();
      return r;
    };
    unsigned lo = 0u, hi = 0x7f7fffffu;
    while (lo < hi) {
      unsigned mid = lo + (hi - lo + 1u) / 2u;
      if (countLossGe(mid) >= k) lo = mid; else hi = mid - 1u;
    }
    unsigned cgt = countLossGe(lo + 1u);
    float s2 = 0.0f;
    for (unsigned e = tid; e < cnt; e += 256) {
      float L = lossf(Gx[e], 0.0f, 0.0f);
      if (selp(e) && __float_as_uint(L) > lo) s2 += L;
    }
    redf[tid] = s2; __syncthreads();
    for (int st = 128; st > 0; st >>= 1) { if (tid < st) redf[tid] += redf[tid + st]; __syncthreads(); }
    if (tid == 0) s_res = redf[0] + (float)(k - cgt) * __uint_as_float(lo);
    __syncthreads();
  }

  if (tid == 0) *(float*)(line + 12) = s_res;
}

__global__ void passC(const char* __restrict__ hdr, float* __restrict__ out)
{
  const int lane = threadIdx.x;
  float ps = 0.0f, ns = 0.0f;
  if (lane < BATCH) {
    const char* line = hdr + (size_t)lane * 256;
    unsigned np = *(const unsigned*)(line + 4);
    float denom = (np > 0u) ? fmaxf((float)np, 1.0f) : 1.0f;
    ps = (*(const float*)(line + 0)) / denom;
    ns = (*(const float*)(line + 12)) / denom;
  }
#pragma unroll
  for (int s = 8; s > 0; s >>= 1) {
    ps += __shfl_down(ps, s, 64);
    ns += __shfl_down(ns, s, 64);
  }
  if (lane == 0 && blockIdx.x == 0) {
    out[0] = ps / (float)BATCH;
    out[1] = ns / (float)BATCH;
  }
}

extern "C" void kernel_launch(void* const* d_in, const int* in_sizes, int n_in,
                              void* d_out, int out_size, void* d_ws, size_t ws_size,
                              hipStream_t stream)
{
  const float* pred   = (const float*)d_in[0];
  const float* target = (const float*)d_in[1];
  const float* mask   = (const float*)d_in[2];
  float* out = (float*)d_out;

  const size_t MASK_BYTES = (size_t)BATCH * NBLK * 4 * 8 * 8;   // 1,769,472
  const size_t FIXED = 4096 + (size_t)BATCH * NBIN * 4
                     + 3 * (size_t)BATCH * BCAP * 4 + MASK_BYTES; // 1,851,392
  size_t avail = (ws_size > FIXED) ? (ws_size - FIXED) : 0;
  unsigned cap = (unsigned)(avail / ((size_t)BATCH * 12));
  if (cap > CAP) cap = CAP;
  if (cap == 0 || out_size < 2) {
    hipMemsetAsync(d_out, 0, sizeof(float) * (out_size > 0 ? out_size : 1), stream);
    return;
  }

  char* ws = (char*)d_ws;
  char*     hdr     = ws;
  unsigned* hist    = (unsigned*)(ws + 4096);
  unsigned* blk_key = (unsigned*)(ws + 4096 + (size_t)BATCH * NBIN * 4);
  unsigned* blk_idx = blk_key + BATCH * BCAP;
  float*    blk_x   = (float*)(blk_idx + BATCH * BCAP);
  unsigned long long* cand_mask =
      (unsigned long long*)(ws + 4096 + (size_t)BATCH * NBIN * 4
                               + 3 * (size_t)BATCH * BCAP * 4);
  unsigned long long* g_rec = (unsigned long long*)(ws + FIXED);
  float*    g_x     = (float*)(ws + FIXED + (size_t)BATCH * cap * 8);

  KeyPairs kp;
  for (unsigned b = 0; b < BATCH; ++b) {
    unsigned o0, o1;
    tf2x32(0u, 42u, 0u, b, o0, o1);
    kp.k[2 * b] = o0; kp.k[2 * b + 1] = o1;
  }

  hipMemsetAsync(ws, 0, 4096 + (size_t)BATCH * NBIN * 4, stream);  // hdr + hist

  passA<<<dim3(NBLK, BATCH), 256, 0, stream>>>(pred, target, mask, hdr,
                                               cand_mask, kp);
  expand<<<dim3(NBLK / EBLK, BATCH), 256, 0, stream>>>(pred, mask, hdr,
                                                       cand_mask, hist,
                                                       g_rec, g_x, cap, kp);
  passB2<<<dim3(16, BATCH), 256, 0, stream>>>(hdr, hist, g_rec, g_x,
                                              blk_key, blk_idx, blk_x, cap);
  passB3<<<BATCH, 256, 0, stream>>>(hdr, g_rec, g_x, blk_key, blk_idx, blk_x, cap);
  passC<<<1, 64, 0, stream>>>(hdr, out);
}